// Round 6
// baseline (616.124 us; speedup 1.0000x reference)
//
#include <hip/hip_runtime.h>

#define Hdim 128
#define Tlen 512
#define BT 4      // batch rows per block -> 512 blocks = 2 blocks/CU
#define STR 136   // padded LDS row stride in fp16 elems (272B = 17x16B)

typedef __attribute__((ext_vector_type(8))) _Float16 f16x8;
typedef __attribute__((ext_vector_type(4))) float f32x4;

__device__ __forceinline__ f32x4 mfma_f16(f16x8 a, f16x8 b, f32x4 c) {
  return __builtin_amdgcn_mfma_f32_16x16x32_f16(a, b, c, 0, 0, 0);
}
// lane i <- lane (i+8) mod 16 within each 16-lane DPP row == lane^8 swap.
__device__ __forceinline__ float dpp_xor8(float v) {
  int r = __builtin_amdgcn_update_dpp(0, __builtin_bit_cast(int, v),
                                      0x128 /*row_ror:8*/, 0xF, 0xF, true);
  return __builtin_bit_cast(float, r);
}
// dest lane i <- src lane i-4 within 16-lane row; lanes 0-3 keep `old`
// (bound_ctrl=false). Rebalances cell r2=1 onto the idle mirror lanes.
__device__ __forceinline__ float dpp_shl4(float old, float v) {
  int r = __builtin_amdgcn_update_dpp(__builtin_bit_cast(int, old),
                                      __builtin_bit_cast(int, v),
                                      0x104 /*row_shl:4*/, 0xF, 0xF, false);
  return __builtin_bit_cast(float, r);
}

// R6: occupancy over FLOPs. 512 blocks x 512 threads (2 blocks/CU, 4 waves/
// SIMD) — decoupled barriers fill the ~50% dependency bubble R5 measured.
// Each block: 4 batch rows (cols 0-3 = h fp16-hi, cols 8-11 = fp16 residual,
// cols 4-7/12-15 dead), all 512 steps. Wave w owns M-tiles {w+8s} = gate
// types i,f,g,o of units 16w..16w+15; 16 MFMA/wave/step. Gate assembly:
// xor8 DPP cross-add (hi+lo cols) -> +bias+x*W_ih via FMA on owner lanes ->
// row_shl:4 DPP spreads to 1 cell/lane -> pointwise fully occupied.
// VGPR must stay <=128 for 4 waves/SIMD (launch_bounds-forced).
__global__ __launch_bounds__(512, 4)
void lstm_disc_kernel(const float* __restrict__ x, const float* __restrict__ hx0,
                      const float* __restrict__ cx0, const float* __restrict__ W_ih,
                      const float* __restrict__ W_hh, const float* __restrict__ b_ih,
                      const float* __restrict__ b_hh, const float* __restrict__ W_mlp,
                      const float* __restrict__ b_mlp, float* __restrict__ out) {
  __shared__ _Float16 hbuf0[16 * STR];
  __shared__ _Float16 hbuf1[16 * STR];

  const int tid  = threadIdx.x;
  const int w    = tid >> 6;          // wave 0..7
  const int lane = tid & 63;
  const int l16  = lane & 15;         // B col n / A row m
  const int quad = lane >> 4;         // 0..3
  const int b0   = blockIdx.x * BT;
  const int bb   = l16 & 3;           // batch row within block
  const int rbase = (l16 < 8) ? 0 : 2;
  const bool owner = ((l16 >> 2) & 1) == 0;   // cols 0-3 & 8-11 are real
  // after rebalance each lane owns exactly one (unit,batch) cell:
  const int row_own = quad * 4 + 2 * (l16 >> 3) + ((l16 >> 2) & 1);
  const int u = 16 * w + row_own;     // hidden unit this lane updates

  // ---- A fragments: W_hh pre-scaled by -log2e (i,f,o) / +2log2e (g) ----
  f16x8 wh[4][4];
  float wihG[4][2], biasG[4][2];      // in G-space (owner lanes, rows m,m+?)
#pragma unroll
  for (int s = 0; s < 4; s++) {
    const float sc = (s == 2) ? 2.88539008f : -1.44269504f;
    const int j = 16 * w + 128 * s + l16;
#pragma unroll
    for (int q = 0; q < 4; q++) {
      const float* p = W_hh + j * Hdim + q * 32 + quad * 8;
      f16x8 f;
#pragma unroll
      for (int e = 0; e < 8; e++) f[e] = (_Float16)(p[e] * sc);
      wh[s][q] = f;
    }
#pragma unroll
    for (int r2 = 0; r2 < 2; r2++) {
      const int j2 = 16 * w + 128 * s + quad * 4 + rbase + r2;
      wihG[s][r2]  = owner ? W_ih[j2] * sc : 0.0f;
      biasG[s][r2] = owner ? (b_ih[j2] + b_hh[j2]) * sc : 0.0f;
    }
  }

  // ---- h0 -> LDS rows 0-3 (hi) / 8-11 (lo); zero dead rows in BOTH bufs ----
  for (int i = tid; i < 16 * Hdim; i += 512) {
    const int r = i >> 7, k = i & 127;
    _Float16 val = (_Float16)0.0f;
    if (r < 4) {
      val = (_Float16)hx0[(b0 + r) * Hdim + k];
    } else if (r >= 8 && r < 12) {
      float v = hx0[(b0 + r - 8) * Hdim + k];
      val = (_Float16)(v - (float)(_Float16)v);
    }
    hbuf0[r * STR + k] = val;
    hbuf1[r * STR + k] = (_Float16)0.0f;   // step-0 writes rows 0-3/8-11 first
  }

  // ---- c0: one cell per lane ----
  float c = cx0[(b0 + bb) * Hdim + u];

  const float* xp = x + (b0 + bb) * Tlen;
  float xv0 = xp[0], xv1 = xp[1];

  __syncthreads();

  const f32x4 Z = {0.0f, 0.0f, 0.0f, 0.0f};

  auto step = [&](const _Float16* __restrict__ src, _Float16* __restrict__ dst,
                  float xv) {
    // B frags: B[k=quad*8+e][n=l16]
    f16x8 bfrag[4];
#pragma unroll
    for (int q = 0; q < 4; q++)
      bfrag[q] = *(const f16x8*)&src[l16 * STR + q * 32 + quad * 8];

    float G0[4], G1[4];
#pragma unroll
    for (int s = 0; s < 4; s++) {
      f32x4 a = mfma_f16(wh[s][0], bfrag[0], Z);
      a = mfma_f16(wh[s][1], bfrag[1], a);
      a = mfma_f16(wh[s][2], bfrag[2], a);
      a = mfma_f16(wh[s][3], bfrag[3], a);
      // hi+lo column cross-add (xor8), then bias + x*W_ih on owner lanes
      float m0 = a[rbase + 0] + dpp_xor8(a[(rbase ^ 2) + 0]);
      float m1 = a[rbase + 1] + dpp_xor8(a[(rbase ^ 2) + 1]);
      G0[s] = __builtin_fmaf(xv, wihG[s][0], m0 + biasG[s][0]);
      G1[s] = __builtin_fmaf(xv, wihG[s][1], m1 + biasG[s][1]);
      // spread cell r2=1 to mirror lane (cols 4-7/12-15) -> 1 cell/lane
      G0[s] = dpp_shl4(G0[s], G1[s]);
    }

    // LSTM pointwise, 1 cell/lane, gates pre-scaled (no mul before exp2)
    float iv = __builtin_amdgcn_rcpf(1.0f + __builtin_amdgcn_exp2f(G0[0]));
    float fv = __builtin_amdgcn_rcpf(1.0f + __builtin_amdgcn_exp2f(G0[1]));
    float gv = 1.0f - 2.0f * __builtin_amdgcn_rcpf(
                            __builtin_amdgcn_exp2f(G0[2]) + 1.0f);
    float ov = __builtin_amdgcn_rcpf(1.0f + __builtin_amdgcn_exp2f(G0[3]));
    float cn = __builtin_fmaf(fv, c, iv * gv);
    c = cn;
    float tc = 1.0f - 2.0f * __builtin_amdgcn_rcpf(
                            __builtin_amdgcn_exp2f(cn * 2.88539008f) + 1.0f);
    float hv = ov * tc;
    _Float16 hh = (_Float16)hv;            // RNE
    dst[bb * STR + u]       = hh;
    dst[(bb + 8) * STR + u] = (_Float16)(hv - (float)hh);

    __syncthreads();
  };

  for (int t = 0; t < Tlen; t += 2) {
    const int tn = t + 2;
    const float xa = xp[(tn     < Tlen) ? tn     : Tlen - 1];
    const float xb = xp[(tn + 1 < Tlen) ? tn + 1 : Tlen - 1];
    step(hbuf0, hbuf1, xv0);
    step(hbuf1, hbuf0, xv1);
    xv0 = xa; xv1 = xb;
  }

  // ---- epilogue: out[b] = sigmoid(h . W_mlp + b_mlp); final h in hbuf0 ----
  if (tid < BT) {
    float s = 0.0f;
#pragma unroll 8
    for (int k = 0; k < Hdim; k++) {
      float hvv = (float)hbuf0[tid * STR + k] + (float)hbuf0[(tid + 8) * STR + k];
      s += hvv * W_mlp[k];
    }
    out[b0 + tid] = __builtin_amdgcn_rcpf(
        1.0f + __builtin_amdgcn_exp2f((s + b_mlp[0]) * -1.44269504f));
  }
}

extern "C" void kernel_launch(void* const* d_in, const int* in_sizes, int n_in,
                              void* d_out, int out_size, void* d_ws, size_t ws_size,
                              hipStream_t stream) {
  const float* x     = (const float*)d_in[0];
  const float* hx0   = (const float*)d_in[1];
  const float* cx0   = (const float*)d_in[2];
  const float* W_ih  = (const float*)d_in[3];
  const float* W_hh  = (const float*)d_in[4];
  const float* b_ih  = (const float*)d_in[5];
  const float* b_hh  = (const float*)d_in[6];
  const float* W_mlp = (const float*)d_in[7];
  const float* b_mlp = (const float*)d_in[8];
  float* out = (float*)d_out;

  const int B = in_sizes[1] / Hdim;   // hx0 is [B, H]
  dim3 grid(B / BT), block(512);
  lstm_disc_kernel<<<grid, block, 0, stream>>>(x, hx0, cx0, W_ih, W_hh, b_ih,
                                               b_hh, W_mlp, b_mlp, out);
}

// Round 7
// 516.307 us; speedup vs baseline: 1.1933x; 1.1933x over previous
//
#include <hip/hip_runtime.h>

#define Hdim 128
#define Tlen 512
#define BT 8      // batch rows per block -> grid 256 = 1 block/CU
#define STR 136   // padded LDS row stride in fp16 elems (272B = 17x16B)

typedef __attribute__((ext_vector_type(8))) _Float16 f16x8;
typedef __attribute__((ext_vector_type(2))) _Float16 f16x2;
typedef __attribute__((ext_vector_type(4))) float f32x4;
typedef __attribute__((ext_vector_type(2))) float f32x2;

__device__ __forceinline__ f32x4 mfma_f16(f16x8 a, f16x8 b, f32x4 c) {
  return __builtin_amdgcn_mfma_f32_16x16x32_f16(a, b, c, 0, 0, 0);
}
// lane i <- lane (i+8) mod 16 within each 16-lane DPP row == lane^8 swap.
__device__ __forceinline__ float dpp_xor8(float v) {
  int r = __builtin_amdgcn_update_dpp(0, __builtin_bit_cast(int, v),
                                      0x128 /*row_ror:8*/, 0xF, 0xF, true);
  return __builtin_bit_cast(float, r);
}
__device__ __forceinline__ f16x2 pk16(float a, float b) {
  return __builtin_bit_cast(f16x2, __builtin_amdgcn_cvt_pkrtz(a, b));
}

// R7: 4 waves/SIMD at CONSTANT chip FLOPs (R6 doubled FLOPs for occupancy —
// regressed). 256 blocks x 1024 threads (16 waves), BT=8. Wave w owns M-tiles
// {w, w+16}: low waves (w<8) = i,g gates of units 16k..16k+15 (k=w&7), high
// waves = f,o of the same units; identical C-layout cell mapping across the
// pair. 8 MFMA/wave/step. Low computes P = sigma(Gi)*tanh(Gg), writes fp32 P
// to LDS (b64, conflict-free); high computes sigma(Gf), sigma(Go) in
// parallel, then after barrier reads P: c = fma(f,c,P); h = o*tanh(c);
// writes h hi/lo (fp16 + residual, R5 layout). Two barriers/step.
// Trans balanced 8/8 per wave. x*W_ih + bias via fp32 FMA in C-layout.
// VGPR <=128 forced for 4 waves/SIMD.
__global__ __launch_bounds__(1024, 4)
void lstm_disc_kernel(const float* __restrict__ x, const float* __restrict__ hx0,
                      const float* __restrict__ cx0, const float* __restrict__ W_ih,
                      const float* __restrict__ W_hh, const float* __restrict__ b_ih,
                      const float* __restrict__ b_hh, const float* __restrict__ W_mlp,
                      const float* __restrict__ b_mlp, float* __restrict__ out) {
  __shared__ _Float16 hbuf0[16 * STR];
  __shared__ _Float16 hbuf1[16 * STR];
  __shared__ float Pbuf[8 * 128];     // P[k][cell], cell = lane*2+r2

  const int tid  = threadIdx.x;
  const int w    = tid >> 6;          // wave 0..15
  const int lane = tid & 63;
  const int l16  = lane & 15;         // B col n / A row m
  const int quad = lane >> 4;         // 0..3
  const int b0   = blockIdx.x * BT;
  const int bb   = l16 & 7;           // batch row within block
  const int rbase = (l16 < 8) ? 0 : 2;
  const int k    = w & 7;             // pair index = unit-set index
  const bool low = (w < 8);           // i,g waves; else f,o waves

  // ---- A fragments: tiles {w, w+16}, W_hh pre-scaled (-log2e sigm, +2log2e tanh) ----
  f16x8 wh[2][4];
  float wihG[2][2], biasG[2][2];
#pragma unroll
  for (int d = 0; d < 2; d++) {
    const int t = w + 16 * d;                   // M-tile
    const float sc = ((t >> 3) == 2) ? 2.88539008f : -1.44269504f;
    const int j = t * 16 + l16;                 // gate row
#pragma unroll
    for (int q = 0; q < 4; q++) {
      const float* p = W_hh + j * Hdim + q * 32 + quad * 8;
      f16x8 f;
#pragma unroll
      for (int e = 0; e < 8; e++) f[e] = (_Float16)(p[e] * sc);
      wh[d][q] = f;
    }
#pragma unroll
    for (int r2 = 0; r2 < 2; r2++) {
      const int j2 = t * 16 + quad * 4 + rbase + r2;
      wihG[d][r2]  = W_ih[j2] * sc;
      biasG[d][r2] = (b_ih[j2] + b_hh[j2]) * sc;
    }
  }

  // ---- h0 -> LDS: rows 0-7 fp16 hi, rows 8-15 fp16 residual ----
  for (int i = tid; i < BT * Hdim; i += 1024) {
    const int b = i >> 7, kk = i & 127;
    float v = hx0[(b0 + b) * Hdim + kk];
    _Float16 h = (_Float16)v;
    hbuf0[b * STR + kk]       = h;
    hbuf0[(b + 8) * STR + kk] = (_Float16)(v - (float)h);
  }

  // ---- c on high waves only: lane owns units u0,u0+1 of batch bb ----
  const int u0 = 16 * k + 4 * quad + rbase;     // even
  float c[2] = {0.0f, 0.0f};
  if (!low) {
    c[0] = cx0[(b0 + bb) * Hdim + u0];
    c[1] = cx0[(b0 + bb) * Hdim + u0 + 1];
  }

  const float* xp = x + (b0 + bb) * Tlen;
  float xv0 = xp[0], xv1 = xp[1];

  __syncthreads();

  const f32x4 Z = {0.0f, 0.0f, 0.0f, 0.0f};
  float* Pslot = &Pbuf[(k * 64 + lane) * 2];

  auto step = [&](const _Float16* __restrict__ src, _Float16* __restrict__ dst,
                  float xv) {
    // B frags: B[k=quad*8+e][n=l16]
    f16x8 bfrag[4];
#pragma unroll
    for (int q = 0; q < 4; q++)
      bfrag[q] = *(const f16x8*)&src[l16 * STR + q * 32 + quad * 8];

    // two independent 4-deep MFMA chains (tiles d=0,1)
    f32x4 a0 = mfma_f16(wh[0][0], bfrag[0], Z);
    f32x4 a1 = mfma_f16(wh[1][0], bfrag[0], Z);
    a0 = mfma_f16(wh[0][1], bfrag[1], a0);
    a1 = mfma_f16(wh[1][1], bfrag[1], a1);
    a0 = mfma_f16(wh[0][2], bfrag[2], a0);
    a1 = mfma_f16(wh[1][2], bfrag[2], a1);
    a0 = mfma_f16(wh[0][3], bfrag[3], a0);
    a1 = mfma_f16(wh[1][3], bfrag[3], a1);

    // fold hi+lo cols (xor8), add bias + x*W_ih (fp32 exact)
    float G0[2], G1[2];
#pragma unroll
    for (int r2 = 0; r2 < 2; r2++) {
      float m0 = a0[rbase + r2] + dpp_xor8(a0[(rbase ^ 2) + r2]);
      float m1 = a1[rbase + r2] + dpp_xor8(a1[(rbase ^ 2) + r2]);
      G0[r2] = __builtin_fmaf(xv, wihG[0][r2], m0 + biasG[0][r2]);
      G1[r2] = __builtin_fmaf(xv, wihG[1][r2], m1 + biasG[1][r2]);
    }

    float fo0[2], fo1[2];
    if (low) {
      // i,g -> P = sigma(Gi)*tanh(Gg) (pre-scaled forms)
      f32x2 P;
#pragma unroll
      for (int r2 = 0; r2 < 2; r2++) {
        float iv = __builtin_amdgcn_rcpf(1.0f + __builtin_amdgcn_exp2f(G0[r2]));
        float gv = 1.0f - 2.0f * __builtin_amdgcn_rcpf(
                                __builtin_amdgcn_exp2f(G1[r2]) + 1.0f);
        P[r2] = iv * gv;
      }
      *(f32x2*)Pslot = P;
    } else {
      // f,o sigmoids (overlap with low's work)
#pragma unroll
      for (int r2 = 0; r2 < 2; r2++) {
        fo0[r2] = __builtin_amdgcn_rcpf(1.0f + __builtin_amdgcn_exp2f(G0[r2]));
        fo1[r2] = __builtin_amdgcn_rcpf(1.0f + __builtin_amdgcn_exp2f(G1[r2]));
      }
    }

    __syncthreads();    // P visible to high waves

    if (!low) {
      f32x2 P = *(const f32x2*)Pslot;
      float hv[2];
#pragma unroll
      for (int r2 = 0; r2 < 2; r2++) {
        float cn = __builtin_fmaf(fo0[r2], c[r2], P[r2]);
        c[r2] = cn;
        float tc = 1.0f - 2.0f * __builtin_amdgcn_rcpf(
                                __builtin_amdgcn_exp2f(cn * 2.88539008f) + 1.0f);
        hv[r2] = fo1[r2] * tc;
      }
      f16x2 hh = pk16(hv[0], hv[1]);
      f16x2 hl = pk16(hv[0] - (float)hh[0], hv[1] - (float)hh[1]);
      *(f16x2*)&dst[bb * STR + u0]       = hh;
      *(f16x2*)&dst[(bb + 8) * STR + u0] = hl;
    }

    __syncthreads();    // h[t+1] complete
  };

  for (int t = 0; t < Tlen; t += 2) {
    const int tn = t + 2;
    const float xa = xp[(tn     < Tlen) ? tn     : Tlen - 1];
    const float xb = xp[(tn + 1 < Tlen) ? tn + 1 : Tlen - 1];
    step(hbuf0, hbuf1, xv0);
    step(hbuf1, hbuf0, xv1);
    xv0 = xa; xv1 = xb;
  }

  // ---- epilogue: out[b] = sigmoid(h . W_mlp + b_mlp); final h in hbuf0 ----
  if (tid < BT) {
    float s = 0.0f;
#pragma unroll 8
    for (int kk = 0; kk < Hdim; kk++) {
      float hvv = (float)hbuf0[tid * STR + kk] + (float)hbuf0[(tid + 8) * STR + kk];
      s += hvv * W_mlp[kk];
    }
    out[b0 + tid] = __builtin_amdgcn_rcpf(
        1.0f + __builtin_amdgcn_exp2f((s + b_mlp[0]) * -1.44269504f));
  }
}

extern "C" void kernel_launch(void* const* d_in, const int* in_sizes, int n_in,
                              void* d_out, int out_size, void* d_ws, size_t ws_size,
                              hipStream_t stream) {
  const float* x     = (const float*)d_in[0];
  const float* hx0   = (const float*)d_in[1];
  const float* cx0   = (const float*)d_in[2];
  const float* W_ih  = (const float*)d_in[3];
  const float* W_hh  = (const float*)d_in[4];
  const float* b_ih  = (const float*)d_in[5];
  const float* b_hh  = (const float*)d_in[6];
  const float* W_mlp = (const float*)d_in[7];
  const float* b_mlp = (const float*)d_in[8];
  float* out = (float*)d_out;

  const int B = in_sizes[1] / Hdim;   // hx0 is [B, H]
  dim3 grid(B / BT), block(1024);
  lstm_disc_kernel<<<grid, block, 0, stream>>>(x, hx0, cx0, W_ih, W_hh, b_ih,
                                               b_hh, W_mlp, b_mlp, out);
}

// Round 8
// 366.815 us; speedup vs baseline: 1.6797x; 1.4075x over previous
//
#include <hip/hip_runtime.h>

#define Hdim 128
#define Tlen 512
#define BT 8      // batch rows per block -> grid 256 = 1 block/CU
#define STR 136   // padded LDS row stride in fp16 elems (272B = 17x16B)

typedef __attribute__((ext_vector_type(8))) _Float16 f16x8;
typedef __attribute__((ext_vector_type(2))) _Float16 f16x2;
typedef __attribute__((ext_vector_type(4))) float f32x4;

__device__ __forceinline__ f32x4 mfma_f16(f16x8 a, f16x8 b, f32x4 c) {
  return __builtin_amdgcn_mfma_f32_16x16x32_f16(a, b, c, 0, 0, 0);
}
// dest lane i (within 16-lane DPP row): i>=8 gets src lane i-8's v; i<8 keeps
// `old` (bound_ctrl=false). Rebalances C-regs 2,3 onto the duplicate lanes.
__device__ __forceinline__ float dpp_shl8(float old, float v) {
  int r = __builtin_amdgcn_update_dpp(__builtin_bit_cast(int, old),
                                      __builtin_bit_cast(int, v),
                                      0x108 /*row_shl:8*/, 0xF, 0xF, false);
  return __builtin_bit_cast(float, r);
}

// R8: R5 structure (8 waves, BT=8, 4 M-tiles/wave, ONE barrier/step) with
// every phase term cut (phase-model validated on R5/R6/R7):
//  - no wx MFMA: x*W_ih + bias folded as 2 scalar fp32 FMAs (16 MFMA/wave)
//  - no residual columns: h is pure fp16 RNE. B cols 8-15 duplicate 0-7
//    (lanes l16 and l16^8 read the SAME LDS address -> bank broadcast ->
//    ds_read traffic ~halves); no xor8 fold needed.
//  - hi-lanes' 4 valid C-regs rebalanced to 2 cells/lane via row_shl:8 DPP.
// Wave w owns M-tiles {w+8s} = gates i,f,g,o of units 16w..16w+15; lane
// (l16,quad) owns units 16w+quad*4+{0,1} (l16<8) or +{2,3} (l16>=8) of batch
// l16&7; c fp32-resident. W pre-scaled by -log2e (i,f,o) / +2log2e (g).
__global__ __launch_bounds__(512, 2)
void lstm_disc_kernel(const float* __restrict__ x, const float* __restrict__ hx0,
                      const float* __restrict__ cx0, const float* __restrict__ W_ih,
                      const float* __restrict__ W_hh, const float* __restrict__ b_ih,
                      const float* __restrict__ b_hh, const float* __restrict__ W_mlp,
                      const float* __restrict__ b_mlp, float* __restrict__ out) {
  __shared__ _Float16 hbuf0[BT * STR];
  __shared__ _Float16 hbuf1[BT * STR];

  const int tid  = threadIdx.x;
  const int w    = tid >> 6;          // wave 0..7
  const int lane = tid & 63;
  const int l16  = lane & 15;         // B col n / A row m
  const int quad = lane >> 4;         // 0..3
  const int b0   = blockIdx.x * BT;
  const int bb   = l16 & 7;           // batch row (cols 8-15 duplicate 0-7)
  const bool hi  = (l16 < 8);
  const int uoff = quad * 4 + (hi ? 0 : 2);   // in-wave unit offset (even)
  const int ub   = 16 * w + uoff;             // first owned unit

  // ---- A fragments: W_hh pre-scaled; x/bias terms in final cell layout ----
  f16x8 wh[4][4];
  float wihG[4][2], biasG[4][2];
#pragma unroll
  for (int s = 0; s < 4; s++) {
    const float sc = (s == 2) ? 2.88539008f : -1.44269504f;  // g : i,f,o
    const int j = 16 * w + 128 * s + l16;       // gate row, type s
#pragma unroll
    for (int q = 0; q < 4; q++) {
      const float* p = W_hh + j * Hdim + q * 32 + quad * 8;
      f16x8 f;
#pragma unroll
      for (int e = 0; e < 8; e++) f[e] = (_Float16)(p[e] * sc);
      wh[s][q] = f;
    }
#pragma unroll
    for (int r2 = 0; r2 < 2; r2++) {
      const int j2 = 16 * w + 128 * s + uoff + r2;
      wihG[s][r2]  = W_ih[j2] * sc;
      biasG[s][r2] = (b_ih[j2] + b_hh[j2]) * sc;
    }
  }

  // ---- h0 -> LDS rows 0-7, fp16 RNE ----
  for (int i = tid; i < BT * Hdim; i += 512) {
    const int b = i >> 7, k = i & 127;
    hbuf0[b * STR + k] = (_Float16)hx0[(b0 + b) * Hdim + k];
  }

  // ---- c0: lane owns units ub, ub+1 of batch bb ----
  float c[2] = {cx0[(b0 + bb) * Hdim + ub], cx0[(b0 + bb) * Hdim + ub + 1]};

  const float* xp = x + (b0 + bb) * Tlen;
  float xv0 = xp[0], xv1 = xp[1];

  __syncthreads();

  const f32x4 Z = {0.0f, 0.0f, 0.0f, 0.0f};

  auto step = [&](const _Float16* __restrict__ src, _Float16* __restrict__ dst,
                  float xv) {
    // B frags: B[k=quad*8+e][n=l16], col n = batch bb (8-15 broadcast-dup)
    f16x8 bfrag[4];
#pragma unroll
    for (int q = 0; q < 4; q++)
      bfrag[q] = *(const f16x8*)&src[bb * STR + q * 32 + quad * 8];

    // four independent 4-deep MFMA chains (gate types i,f,g,o)
    f32x4 a[4];
#pragma unroll
    for (int s = 0; s < 4; s++) a[s] = mfma_f16(wh[s][0], bfrag[0], Z);
#pragma unroll
    for (int q = 1; q < 4; q++)
#pragma unroll
      for (int s = 0; s < 4; s++) a[s] = mfma_f16(wh[s][q], bfrag[q], a[s]);

    // rebalance: lanes >=8 take regs 2,3 from lane-8; add bias + x*W_ih
    float G[4][2];
#pragma unroll
    for (int s = 0; s < 4; s++)
#pragma unroll
      for (int r2 = 0; r2 < 2; r2++) {
        float g = dpp_shl8(a[s][r2], a[s][2 + r2]);
        G[s][r2] = __builtin_fmaf(xv, wihG[s][r2], g + biasG[s][r2]);
      }

    // LSTM pointwise, 2 cells/lane, gates pre-scaled (no mul before exp2)
    float hv[2];
#pragma unroll
    for (int r2 = 0; r2 < 2; r2++) {
      float iv = __builtin_amdgcn_rcpf(1.0f + __builtin_amdgcn_exp2f(G[0][r2]));
      float fv = __builtin_amdgcn_rcpf(1.0f + __builtin_amdgcn_exp2f(G[1][r2]));
      float gv = 1.0f - 2.0f * __builtin_amdgcn_rcpf(
                              __builtin_amdgcn_exp2f(G[2][r2]) + 1.0f);
      float ov = __builtin_amdgcn_rcpf(1.0f + __builtin_amdgcn_exp2f(G[3][r2]));
      float cn = __builtin_fmaf(fv, c[r2], iv * gv);
      c[r2] = cn;
      float tc = 1.0f - 2.0f * __builtin_amdgcn_rcpf(
                              __builtin_amdgcn_exp2f(cn * 2.88539008f) + 1.0f);
      hv[r2] = ov * tc;
    }
    f16x2 hp;
    hp[0] = (_Float16)hv[0];   // RNE
    hp[1] = (_Float16)hv[1];
    *(f16x2*)&dst[bb * STR + ub] = hp;

    __syncthreads();
  };

  for (int t = 0; t < Tlen; t += 2) {
    const int tn = t + 2;
    const float xa = xp[(tn     < Tlen) ? tn     : Tlen - 1];
    const float xb = xp[(tn + 1 < Tlen) ? tn + 1 : Tlen - 1];
    step(hbuf0, hbuf1, xv0);
    step(hbuf1, hbuf0, xv1);
    xv0 = xa; xv1 = xb;
  }

  // ---- epilogue: out[b] = sigmoid(h . W_mlp + b_mlp); final h in hbuf0 ----
  if (tid < BT) {
    float s = 0.0f;
#pragma unroll 8
    for (int k = 0; k < Hdim; k++)
      s += (float)hbuf0[tid * STR + k] * W_mlp[k];
    out[b0 + tid] = __builtin_amdgcn_rcpf(
        1.0f + __builtin_amdgcn_exp2f((s + b_mlp[0]) * -1.44269504f));
  }
}

extern "C" void kernel_launch(void* const* d_in, const int* in_sizes, int n_in,
                              void* d_out, int out_size, void* d_ws, size_t ws_size,
                              hipStream_t stream) {
  const float* x     = (const float*)d_in[0];
  const float* hx0   = (const float*)d_in[1];
  const float* cx0   = (const float*)d_in[2];
  const float* W_ih  = (const float*)d_in[3];
  const float* W_hh  = (const float*)d_in[4];
  const float* b_ih  = (const float*)d_in[5];
  const float* b_hh  = (const float*)d_in[6];
  const float* W_mlp = (const float*)d_in[7];
  const float* b_mlp = (const float*)d_in[8];
  float* out = (float*)d_out;

  const int B = in_sizes[1] / Hdim;   // hx0 is [B, H]
  dim3 grid(B / BT), block(512);
  lstm_disc_kernel<<<grid, block, 0, stream>>>(x, hx0, cx0, W_ih, W_hh, b_ih,
                                               b_hh, W_mlp, b_mlp, out);
}

// Round 10
// 364.013 us; speedup vs baseline: 1.6926x; 1.0077x over previous
//
#include <hip/hip_runtime.h>

#define Hdim 128
#define Tlen 512
#define BT 8      // batch rows per block -> grid 256 = 1 block/CU
#define STR 136   // padded LDS row stride in fp16 elems (272B = 17x16B)

typedef __attribute__((ext_vector_type(8))) _Float16 f16x8;
typedef __attribute__((ext_vector_type(2))) _Float16 f16x2;
typedef __attribute__((ext_vector_type(4))) float f32x4;

__device__ __forceinline__ f32x4 mfma_f16(f16x8 a, f16x8 b, f32x4 c) {
  return __builtin_amdgcn_mfma_f32_16x16x32_f16(a, b, c, 0, 0, 0);
}
// dest lane i (within 16-lane DPP row): i>=8 gets src lane i-8's v; i<8 keeps
// `old` (bound_ctrl=false). Rebalances C-regs 2,3 onto the duplicate lanes.
__device__ __forceinline__ float dpp_shl8(float old, float v) {
  int r = __builtin_amdgcn_update_dpp(__builtin_bit_cast(int, old),
                                      __builtin_bit_cast(int, v),
                                      0x108 /*row_shl:8*/, 0xF, 0xF, false);
  return __builtin_bit_cast(float, r);
}

// R10 = R8 bit-exact (known-good: 367 us, absmax 0.0078125 = 80% of budget)
// + numerics-free unroll-4. R9's lesson: at >50% error-budget utilization,
// only bit-identical transforms are admissible — bias-in-C-operand and
// compiler-chosen FMA contraction re-rolled the chaotic 512-step trajectory
// and doubled absmax. Every fp op in this t-loop is bit-identical to R8:
// bias added post-MFMA as (g + biasG); cn via explicit fma(fv, c, iv*gv);
// trans forms verbatim.
// Structure (phase-serial floor ~1500-1650 cyc/step, all alternatives
// measured worse: R5 residual +25%, R6 BT=4 +73%, R7 16-wave +45%):
// 8 waves, BT=8, wave w owns M-tiles {w+8s} = gates i,f,g,o of units
// 16w..16w+15; B cols 8-15 duplicate 0-7 (bank-broadcast); h fp16 RNE;
// c fp32-resident; one barrier/step; W pre-scaled -log2e (i,f,o) / +2log2e (g).
__global__ __launch_bounds__(512, 2)
void lstm_disc_kernel(const float* __restrict__ x, const float* __restrict__ hx0,
                      const float* __restrict__ cx0, const float* __restrict__ W_ih,
                      const float* __restrict__ W_hh, const float* __restrict__ b_ih,
                      const float* __restrict__ b_hh, const float* __restrict__ W_mlp,
                      const float* __restrict__ b_mlp, float* __restrict__ out) {
  __shared__ _Float16 hbuf0[BT * STR];
  __shared__ _Float16 hbuf1[BT * STR];

  const int tid  = threadIdx.x;
  const int w    = tid >> 6;          // wave 0..7
  const int lane = tid & 63;
  const int l16  = lane & 15;         // B col n / A row m
  const int quad = lane >> 4;         // 0..3
  const int b0   = blockIdx.x * BT;
  const int bb   = l16 & 7;           // batch row (cols 8-15 duplicate 0-7)
  const bool hi  = (l16 < 8);
  const int uoff = quad * 4 + (hi ? 0 : 2);   // in-wave unit offset (even)
  const int ub   = 16 * w + uoff;             // first owned unit

  // ---- A fragments: W_hh pre-scaled; x/bias terms in final cell layout ----
  f16x8 wh[4][4];
  float wihG[4][2], biasG[4][2];
#pragma unroll
  for (int s = 0; s < 4; s++) {
    const float sc = (s == 2) ? 2.88539008f : -1.44269504f;  // g : i,f,o
    const int j = 16 * w + 128 * s + l16;       // gate row, type s
#pragma unroll
    for (int q = 0; q < 4; q++) {
      const float* p = W_hh + j * Hdim + q * 32 + quad * 8;
      f16x8 f;
#pragma unroll
      for (int e = 0; e < 8; e++) f[e] = (_Float16)(p[e] * sc);
      wh[s][q] = f;
    }
#pragma unroll
    for (int r2 = 0; r2 < 2; r2++) {
      const int j2 = 16 * w + 128 * s + uoff + r2;
      wihG[s][r2]  = W_ih[j2] * sc;
      biasG[s][r2] = (b_ih[j2] + b_hh[j2]) * sc;
    }
  }

  // ---- h0 -> LDS rows 0-7, fp16 RNE ----
  for (int i = tid; i < BT * Hdim; i += 512) {
    const int b = i >> 7, k = i & 127;
    hbuf0[b * STR + k] = (_Float16)hx0[(b0 + b) * Hdim + k];
  }

  // ---- c0: lane owns units ub, ub+1 of batch bb ----
  float c[2] = {cx0[(b0 + bb) * Hdim + ub], cx0[(b0 + bb) * Hdim + ub + 1]};

  const float* xp = x + (b0 + bb) * Tlen;
  float xv[4] = {xp[0], xp[1], xp[2], xp[3]};

  __syncthreads();

  const f32x4 Z = {0.0f, 0.0f, 0.0f, 0.0f};

  auto step = [&](const _Float16* __restrict__ src, _Float16* __restrict__ dst,
                  float xcur) {
    // B frags: B[k=quad*8+e][n=l16], col n = batch bb (8-15 broadcast-dup)
    f16x8 bfrag[4];
#pragma unroll
    for (int q = 0; q < 4; q++)
      bfrag[q] = *(const f16x8*)&src[bb * STR + q * 32 + quad * 8];

    // four independent 4-deep MFMA chains (gate types i,f,g,o)
    f32x4 a[4];
#pragma unroll
    for (int s = 0; s < 4; s++) a[s] = mfma_f16(wh[s][0], bfrag[0], Z);
#pragma unroll
    for (int q = 1; q < 4; q++)
#pragma unroll
      for (int s = 0; s < 4; s++) a[s] = mfma_f16(wh[s][q], bfrag[q], a[s]);

    // rebalance: lanes >=8 take regs 2,3 from lane-8; add bias + x*W_ih
    float G[4][2];
#pragma unroll
    for (int s = 0; s < 4; s++)
#pragma unroll
      for (int r2 = 0; r2 < 2; r2++) {
        float g = dpp_shl8(a[s][r2], a[s][2 + r2]);
        G[s][r2] = __builtin_fmaf(xcur, wihG[s][r2], g + biasG[s][r2]);
      }

    // LSTM pointwise, 2 cells/lane, gates pre-scaled (no mul before exp2)
    float hv[2];
#pragma unroll
    for (int r2 = 0; r2 < 2; r2++) {
      float iv = __builtin_amdgcn_rcpf(1.0f + __builtin_amdgcn_exp2f(G[0][r2]));
      float fv = __builtin_amdgcn_rcpf(1.0f + __builtin_amdgcn_exp2f(G[1][r2]));
      float gv = 1.0f - 2.0f * __builtin_amdgcn_rcpf(
                              __builtin_amdgcn_exp2f(G[2][r2]) + 1.0f);
      float ov = __builtin_amdgcn_rcpf(1.0f + __builtin_amdgcn_exp2f(G[3][r2]));
      float cn = __builtin_fmaf(fv, c[r2], iv * gv);
      c[r2] = cn;
      float tc = 1.0f - 2.0f * __builtin_amdgcn_rcpf(
                              __builtin_amdgcn_exp2f(cn * 2.88539008f) + 1.0f);
      hv[r2] = ov * tc;
    }
    f16x2 hp;
    hp[0] = (_Float16)hv[0];   // RNE
    hp[1] = (_Float16)hv[1];
    *(f16x2*)&dst[bb * STR + ub] = hp;

    __syncthreads();
  };

  for (int t = 0; t < Tlen; t += 4) {
    const int tn = t + 4;
    float xa = xp[(tn     < Tlen) ? tn     : Tlen - 1];
    float xb = xp[(tn + 1 < Tlen) ? tn + 1 : Tlen - 1];
    float xc = xp[(tn + 2 < Tlen) ? tn + 2 : Tlen - 1];
    float xd = xp[(tn + 3 < Tlen) ? tn + 3 : Tlen - 1];
    step(hbuf0, hbuf1, xv[0]);
    step(hbuf1, hbuf0, xv[1]);
    step(hbuf0, hbuf1, xv[2]);
    step(hbuf1, hbuf0, xv[3]);
    xv[0] = xa; xv[1] = xb; xv[2] = xc; xv[3] = xd;
  }

  // ---- epilogue: out[b] = sigmoid(h . W_mlp + b_mlp); final h in hbuf0 ----
  if (tid < BT) {
    float s = 0.0f;
#pragma unroll 8
    for (int k = 0; k < Hdim; k++)
      s += (float)hbuf0[tid * STR + k] * W_mlp[k];
    out[b0 + tid] = __builtin_amdgcn_rcpf(
        1.0f + __builtin_amdgcn_exp2f((s + b_mlp[0]) * -1.44269504f));
  }
}

extern "C" void kernel_launch(void* const* d_in, const int* in_sizes, int n_in,
                              void* d_out, int out_size, void* d_ws, size_t ws_size,
                              hipStream_t stream) {
  const float* x     = (const float*)d_in[0];
  const float* hx0   = (const float*)d_in[1];
  const float* cx0   = (const float*)d_in[2];
  const float* W_ih  = (const float*)d_in[3];
  const float* W_hh  = (const float*)d_in[4];
  const float* b_ih  = (const float*)d_in[5];
  const float* b_hh  = (const float*)d_in[6];
  const float* W_mlp = (const float*)d_in[7];
  const float* b_mlp = (const float*)d_in[8];
  float* out = (float*)d_out;

  const int B = in_sizes[1] / Hdim;   // hx0 is [B, H]
  dim3 grid(B / BT), block(512);
  lstm_disc_kernel<<<grid, block, 0, stream>>>(x, hx0, cx0, W_ih, W_hh, b_ih,
                                               b_hh, W_mlp, b_mlp, out);
}